// Round 7
// baseline (399.908 us; speedup 1.0000x reference)
//
#include <hip/hip_runtime.h>
#include <hip/hip_bf16.h>

typedef __hip_bfloat16 bf16;
typedef unsigned short u16;

#define NC 8192
#define NF 32768
#define KNN 16
#define FMAXV 3.402823466e+38f

__device__ __forceinline__ float bfbits2f(u16 u){
  union { unsigned u; float f; } x; x.u = ((unsigned)u) << 16; return x.f;
}

// ---------- one-time prep: pos4 (x,y,z,|d|^2/2) + weight swizzles ----------
// grid 256 blocks x 256 = 65536 threads == total work items (ranges below)
__global__ __launch_bounds__(256) void k_prep(const float* __restrict__ dpos,
                                              const float* __restrict__ Wk,
                                              const float* __restrict__ Wv,
                                              const float* __restrict__ W1,
                                              const float* __restrict__ W2,
                                              const float* __restrict__ Wq,
                                              float4* __restrict__ pos4,
                                              float4* __restrict__ WkS,
                                              float4* __restrict__ WvS,
                                              float4* __restrict__ W1aS,
                                              float4* __restrict__ WqS,
                                              float4* __restrict__ W1eSa,
                                              float4* __restrict__ W1eSb,
                                              float4* __restrict__ W2Sa,
                                              float4* __restrict__ W2Sb){
  int g = blockIdx.x * 256 + threadIdx.x;
  if (g < 8192){
    float x = dpos[g * 3 + 0], y = dpos[g * 3 + 1], z = dpos[g * 3 + 2];
    float dd = __fadd_rn(__fadd_rn(__fmul_rn(x,x), __fmul_rn(y,y)), __fmul_rn(z,z));
    pos4[g] = make_float4(x, y, z, dd * 0.5f);
  } else if (g < 24576){
    int f = g - 8192; int c4 = f >> 8, t = f & 255;
    WkS[f] = ((const float4*)(Wk + (size_t)t * 256))[c4];
  } else if (g < 40960){
    int f = g - 24576; int c4 = f >> 8, t = f & 255;
    WvS[f] = ((const float4*)(Wv + (size_t)t * 256))[c4];
  } else if (g < 49152){
    int f = g - 40960; int c4 = f >> 7, h = f & 127;
    W1aS[f] = ((const float4*)(W1 + (size_t)h * 384))[c4];
  } else if (g < 51200){
    int f = g - 49152; int c4 = f >> 6, jg = f & 63;
    W1eSa[f] = ((const float4*)(W1 + (size_t)(2 * jg) * 384 + 256))[c4];
  } else if (g < 53248){
    int f = g - 51200; int c4 = f >> 6, jg = f & 63;
    W1eSb[f] = ((const float4*)(W1 + (size_t)(2 * jg + 1) * 384 + 256))[c4];
  } else if (g < 55296){
    int f = g - 53248; int c4 = f >> 6, jg = f & 63;
    W2Sa[f] = ((const float4*)(W2 + (size_t)(2 * jg) * 128))[c4];
  } else if (g < 57344){
    int f = g - 55296; int c4 = f >> 6, jg = f & 63;
    W2Sb[f] = ((const float4*)(W2 + (size_t)(2 * jg + 1) * 128))[c4];
  } else if (g < 65536){
    // WqS: 8192 entries exactly (Wq is 256x128). j4 in [0,64), c in [0,128).
    int f = g - 57344; int j4 = f >> 7, c = f & 127;
    WqS[f] = make_float4(Wq[(size_t)(j4 * 4 + 0) * 128 + c],
                         Wq[(size_t)(j4 * 4 + 1) * 128 + c],
                         Wq[(size_t)(j4 * 4 + 2) * 128 + c],
                         Wq[(size_t)(j4 * 4 + 3) * 128 + c]);
  }
}

// ---------- k_dec1: K = df@Wk^T + bk, V = df@Wv^T + bv  -> global f32 ----------
// Activations read with block-uniform addresses (scalar-load path); no LDS.
__global__ __launch_bounds__(256) void k_dec1(const float* __restrict__ df,
                                              const float4* __restrict__ WkS, const float* __restrict__ bk,
                                              const float4* __restrict__ WvS, const float* __restrict__ bv,
                                              float* __restrict__ Kg, float* __restrict__ Vg){
  int t = threadIdx.x;
  int g0 = blockIdx.x * 16;
  float accK[16], accV[16];
  #pragma unroll
  for (int p = 0; p < 16; ++p){ accK[p] = 0.f; accV[p] = 0.f; }
  for (int c4 = 0; c4 < 64; ++c4){
    float4 wk = WkS[c4 * 256 + t];
    float4 wv = WvS[c4 * 256 + t];
    #pragma unroll
    for (int p = 0; p < 16; ++p){
      float4 a = ((const float4*)(df + (size_t)(g0 + p) * 256))[c4];   // uniform -> s_load
      accK[p] += wk.x*a.x + wk.y*a.y + wk.z*a.z + wk.w*a.w;
      accV[p] += wv.x*a.x + wv.y*a.y + wv.z*a.z + wv.w*a.w;
    }
  }
  float bkj = bk[t], bvj = bv[t];
  #pragma unroll
  for (int p = 0; p < 16; ++p){
    Kg[(size_t)(g0 + p) * 256 + t] = accK[p] + bkj;
    Vg[(size_t)(g0 + p) * 256 + t] = accV[p] + bvj;
  }
}

// ---------- k_dec2: Zd = K@Wq, Ud = V@W1a^T, bqK = K.bq ----------
// waves 0-1: Zd from K; waves 2-3: Ud from V. Row data via uniform loads.
__global__ __launch_bounds__(256) void k_dec2(const float* __restrict__ Kg,
                                              const float* __restrict__ Vg,
                                              const float4* __restrict__ WqS,
                                              const float4* __restrict__ W1aS,
                                              const float* __restrict__ bq,
                                              bf16* __restrict__ Zd, bf16* __restrict__ Ud,
                                              float* __restrict__ bqK){
  int t = threadIdx.x;
  int g0 = blockIdx.x * 16;
  int half = __builtin_amdgcn_readfirstlane(t >> 7);
  int c = t & 127;
  const float*  src = half ? Vg : Kg;
  const float4* W   = half ? W1aS : WqS;
  float acc[16];
  #pragma unroll
  for (int p = 0; p < 16; ++p) acc[p] = 0.f;
  for (int j4 = 0; j4 < 64; ++j4){
    float4 w = W[j4 * 128 + c];
    #pragma unroll
    for (int p = 0; p < 16; ++p){
      float4 a = ((const float4*)(src + (size_t)(g0 + p) * 256))[j4];  // uniform -> s_load
      acc[p] += w.x*a.x + w.y*a.y + w.z*a.z + w.w*a.w;
    }
  }
  bf16* dst = half ? Ud : Zd;
  #pragma unroll
  for (int p = 0; p < 16; ++p)
    dst[(size_t)(g0 + p) * 128 + c] = __float2bfloat16(acc[p]);
  if (t < 16){
    float s = 0.f;
    for (int j = 0; j < 256; ++j) s += bq[j] * Kg[(size_t)(g0 + t) * 256 + j];
    bqK[g0 + t] = s;
  }
}

// ---------- fused KNN + attention (two-pass filtered top-16; 3-FMA folded eval) ----------
__global__ __launch_bounds__(256) void k_attn(const float* __restrict__ epos,
                                              const float4* __restrict__ pos4,
                                              const float* __restrict__ ef,
                                              const bf16* __restrict__ Zd,
                                              const bf16* __restrict__ Ud,
                                              const float* __restrict__ bqK,
                                              bf16* __restrict__ hagg){
  __shared__ float smin[4 * 64];
  __shared__ float tauLDS[4];
  __shared__ int   cnt[4];
  __shared__ float lval[4][64];
  __shared__ int   lidx[4][64];

  int t = threadIdx.x, lane = t & 63, w = t >> 6;
  int n0 = blockIdx.x * 4;
  float nex[4], ney[4], nez[4];
  #pragma unroll
  for (int p = 0; p < 4; ++p){
    nex[p] = -epos[(n0 + p) * 3 + 0];
    ney[p] = -epos[(n0 + p) * 3 + 1];
    nez[p] = -epos[(n0 + p) * 3 + 2];
  }
  const float4* base = pos4 + w * 2048;

  // PASS A: per-lane minima of val = dd/2 - e.d  (3 fused FMAs)
  float vmin[4] = {FMAXV, FMAXV, FMAXV, FMAXV};
  #pragma unroll 4
  for (int s = 0; s < 32; ++s){
    float4 P = base[s * 64 + lane];
    #pragma unroll
    for (int p = 0; p < 4; ++p){
      float val = fmaf(nez[p], P.z, fmaf(ney[p], P.y, fmaf(nex[p], P.x, P.w)));
      vmin[p] = fminf(vmin[p], val);
    }
  }
  #pragma unroll
  for (int k = 2; k <= 64; k <<= 1){
    #pragma unroll
    for (int j = k >> 1; j > 0; j >>= 1){
      bool keepmin = ((lane & j) == 0) == ((lane & k) == 0);
      #pragma unroll
      for (int p = 0; p < 4; ++p){
        float pv = __shfl_xor(vmin[p], j);
        vmin[p] = keepmin ? fminf(vmin[p], pv) : fmaxf(vmin[p], pv);
      }
    }
  }
  if (lane < 16){
    #pragma unroll
    for (int p = 0; p < 4; ++p) smin[p * 64 + w * 16 + lane] = vmin[p];
  }
  if (t < 4) cnt[t] = 0;
  __syncthreads();
  {
    float v = smin[w * 64 + lane];
    #pragma unroll
    for (int k = 2; k <= 64; k <<= 1){
      #pragma unroll
      for (int j = k >> 1; j > 0; j >>= 1){
        float pv = __shfl_xor(v, j);
        bool keepmin = ((lane & j) == 0) == ((lane & k) == 0);
        v = keepmin ? fminf(v, pv) : fmaxf(v, pv);
      }
    }
    if (lane == 16) tauLDS[w] = v;
  }
  __syncthreads();
  float tau0[4];
  #pragma unroll
  for (int p = 0; p < 4; ++p) tau0[p] = tauLDS[p];

  // PASS B: filtered append (identical val expression)
  #pragma unroll 2
  for (int s = 0; s < 32; ++s){
    float4 P = base[s * 64 + lane];
    int cand = w * 2048 + s * 64 + lane;
    #pragma unroll
    for (int p = 0; p < 4; ++p){
      float val = fmaf(nez[p], P.z, fmaf(ney[p], P.y, fmaf(nex[p], P.x, P.w)));
      if (val <= tau0[p]){
        int slot = atomicAdd(&cnt[p], 1);
        if (slot < 64){ lval[p][slot] = val; lidx[p][slot] = cand; }
      }
    }
  }
  __syncthreads();

  // wave w finalizes point w: exact (val,idx) bitonic sort, top-16 in lanes 0..15
  int n = n0 + w;
  int c = cnt[w]; if (c > 64) c = 64;
  float v  = (lane < c) ? lval[w][lane] : FMAXV;
  int   id = (lane < c) ? lidx[w][lane] : 0x7fffffff;
  #pragma unroll
  for (int k = 2; k <= 64; k <<= 1){
    #pragma unroll
    for (int j = k >> 1; j > 0; j >>= 1){
      float pv  = __shfl_xor(v, j);
      int   pid = __shfl_xor(id, j);
      bool keepmin = ((lane & j) == 0) == ((lane & k) == 0);
      bool pless = (pv < v) || (pv == v && pid < id);
      bool take = keepmin ? pless : !pless;
      if (take){ v = pv; id = pid; }
    }
  }
  int topi = id;

  // scores: sc_k = (ef[n] . Zd[ik] + bqK[ik]) / 16
  float2 eu = *(const float2*)(ef + (size_t)n * 128 + lane * 2);
  float sc = -FMAXV;
  #pragma unroll
  for (int k = 0; k < KNN; ++k){
    int ik = __shfl(topi, k);
    ushort2 zu = *(const ushort2*)((const u16*)Zd + (size_t)ik * 128 + lane * 2);
    float p = eu.x * bfbits2f(zu.x) + eu.y * bfbits2f(zu.y);
    #pragma unroll
    for (int off = 32; off >= 1; off >>= 1) p += __shfl_xor(p, off);
    float bz = bqK[ik];
    if (lane == k) sc = (p + bz) * (1.0f / 16.0f);
  }
  float mx = sc;
  #pragma unroll
  for (int off = 8; off >= 1; off >>= 1) mx = fmaxf(mx, __shfl_xor(mx, off));
  float e = (lane < KNN) ? __expf(sc - mx) : 0.f;
  float l = e;
  #pragma unroll
  for (int off = 8; off >= 1; off >>= 1) l += __shfl_xor(l, off);
  float wgt = (lane < KNN) ? (e / l) : 0.f;

  float a0 = 0.f, a1 = 0.f;
  #pragma unroll
  for (int k = 0; k < KNN; ++k){
    int ik = __shfl(topi, k);
    float wk = __shfl(wgt, k);
    ushort2 uu = *(const ushort2*)((const u16*)Ud + (size_t)ik * 128 + lane * 2);
    a0 = fmaf(wk, bfbits2f(uu.x), a0);
    a1 = fmaf(wk, bfbits2f(uu.y), a1);
  }
  bf16* hr = hagg + (size_t)n * 128 + lane * 2;
  hr[0] = __float2bfloat16(a0);
  hr[1] = __float2bfloat16(a1);
}

// ---------- k_mlp1: h = relu(hagg + W1e@ef + b1) -> global f32 ----------
__global__ __launch_bounds__(256) void k_mlp1(const bf16* __restrict__ hagg,
                                              const float* __restrict__ ef,
                                              const float4* __restrict__ W1eSa,
                                              const float4* __restrict__ W1eSb,
                                              const float* __restrict__ b1,
                                              float* __restrict__ hg){
  int t = threadIdx.x;
  int jg = t & 63;
  int pg4 = __builtin_amdgcn_readfirstlane((t >> 6) * 4);
  int n0 = blockIdx.x * 16;
  int j0 = jg * 2;
  float acc[2][4];
  #pragma unroll
  for (int a = 0; a < 2; ++a)
    #pragma unroll
    for (int p = 0; p < 4; ++p) acc[a][p] = 0.f;
  for (int c4 = 0; c4 < 32; ++c4){
    float4 wa = W1eSa[c4 * 64 + jg];
    float4 wb = W1eSb[c4 * 64 + jg];
    #pragma unroll
    for (int p = 0; p < 4; ++p){
      float4 x = ((const float4*)(ef + (size_t)(n0 + pg4 + p) * 128))[c4];  // uniform
      acc[0][p] += wa.x*x.x + wa.y*x.y + wa.z*x.z + wa.w*x.w;
      acc[1][p] += wb.x*x.x + wb.y*x.y + wb.z*x.z + wb.w*x.w;
    }
  }
  float b1a = b1[j0], b1b = b1[j0 + 1];
  #pragma unroll
  for (int p = 0; p < 4; ++p){
    size_t row = (size_t)(n0 + pg4 + p);
    ushort2 hgv = *(const ushort2*)((const u16*)hagg + row * 128 + j0);
    float h0 = fmaxf(acc[0][p] + b1a + bfbits2f(hgv.x), 0.f);
    float h1 = fmaxf(acc[1][p] + b1b + bfbits2f(hgv.y), 0.f);
    *(float2*)(hg + row * 128 + j0) = make_float2(h0, h1);
  }
}

// ---------- k_mlp2: up = W2@h + b2; LayerNorm; out (+ fused passthrough tail) ----------
__global__ __launch_bounds__(256) void k_mlp2(const float* __restrict__ hg,
                                              const float4* __restrict__ W2Sa,
                                              const float4* __restrict__ W2Sb,
                                              const float* __restrict__ b2,
                                              const float* __restrict__ lng, const float* __restrict__ lnb,
                                              const float* __restrict__ epos, const int* __restrict__ lab,
                                              float* __restrict__ out){
  __shared__ float ubuf[16 * 128];
  __shared__ float stats[32];
  int t = threadIdx.x;
  int n0 = blockIdx.x * 16;
  {
    int gid = blockIdx.x * 256 + t;
    if (gid < NF){
      float* op = out + (size_t)NF * 128;
      op[gid * 3 + 0] = epos[gid * 3 + 0];
      op[gid * 3 + 1] = epos[gid * 3 + 1];
      op[gid * 3 + 2] = epos[gid * 3 + 2];
      out[(size_t)NF * 128 + (size_t)NF * 3 + gid] = (float)lab[gid];
    }
  }
  int jg = t & 63;
  int pg4 = __builtin_amdgcn_readfirstlane((t >> 6) * 4);
  int j0 = jg * 2;
  float acc2[2][4];
  #pragma unroll
  for (int a = 0; a < 2; ++a)
    #pragma unroll
    for (int p = 0; p < 4; ++p) acc2[a][p] = 0.f;
  for (int c4 = 0; c4 < 32; ++c4){
    float4 wa = W2Sa[c4 * 64 + jg];
    float4 wb = W2Sb[c4 * 64 + jg];
    #pragma unroll
    for (int p = 0; p < 4; ++p){
      float4 x = ((const float4*)(hg + (size_t)(n0 + pg4 + p) * 128))[c4];  // uniform
      acc2[0][p] += wa.x*x.x + wa.y*x.y + wa.z*x.z + wa.w*x.w;
      acc2[1][p] += wb.x*x.x + wb.y*x.y + wb.z*x.z + wb.w*x.w;
    }
  }
  float b2a = b2[j0], b2b = b2[j0 + 1];
  float u[2][4];
  #pragma unroll
  for (int p = 0; p < 4; ++p){
    u[0][p] = acc2[0][p] + b2a;
    u[1][p] = acc2[1][p] + b2b;
    ubuf[(pg4 + p) * 128 + j0]     = u[0][p];
    ubuf[(pg4 + p) * 128 + j0 + 1] = u[1][p];
  }
  __syncthreads();
  {
    int p = t >> 4, qi = t & 15;
    const float* ub = &ubuf[p * 128 + qi * 8];
    float s = 0.f, s2 = 0.f;
    #pragma unroll
    for (int e2i = 0; e2i < 8; ++e2i){ float v = ub[e2i]; s += v; s2 += v * v; }
    #pragma unroll
    for (int off = 1; off < 16; off <<= 1){ s += __shfl_xor(s, off); s2 += __shfl_xor(s2, off); }
    if (qi == 0){
      float mu = s * (1.f / 128.f);
      float var = s2 * (1.f / 128.f) - mu * mu;
      stats[p] = mu;
      stats[16 + p] = rsqrtf(fmaxf(var, 0.f) + 1e-5f);
    }
  }
  __syncthreads();
  float ga = lng[j0], gb = lng[j0 + 1];
  float ba = lnb[j0], bbv = lnb[j0 + 1];
  #pragma unroll
  for (int p = 0; p < 4; ++p){
    float mu = stats[pg4 + p], rs = stats[16 + pg4 + p];
    out[(size_t)(n0 + pg4 + p) * 128 + j0]     = (u[0][p] - mu) * rs * ga + ba;
    out[(size_t)(n0 + pg4 + p) * 128 + j0 + 1] = (u[1][p] - mu) * rs * gb + bbv;
  }
}

extern "C" void kernel_launch(void* const* d_in, const int* in_sizes, int n_in,
                              void* d_out, int out_size, void* d_ws, size_t ws_size,
                              hipStream_t stream){
  const float* df   = (const float*)d_in[0];
  const float* dpos = (const float*)d_in[1];
  const float* ef   = (const float*)d_in[2];
  const float* epos = (const float*)d_in[3];
  const int*   lab  = (const int*)d_in[4];
  const float* Wq = (const float*)d_in[5];
  const float* bq = (const float*)d_in[6];
  const float* Wk = (const float*)d_in[7];
  const float* bk = (const float*)d_in[8];
  const float* Wv = (const float*)d_in[9];
  const float* bv = (const float*)d_in[10];
  const float* W1 = (const float*)d_in[11];
  const float* b1 = (const float*)d_in[12];
  const float* W2 = (const float*)d_in[13];
  const float* b2 = (const float*)d_in[14];
  const float* lng = (const float*)d_in[15];
  const float* lnb = (const float*)d_in[16];
  float* out = (float*)d_out;

  // workspace layout (~29 MB); hg overlays Kg/Vg (written strictly after k_dec2)
  char* wsb = (char*)d_ws;
  float4* pos4  = (float4*)(wsb);                    // 131072 B
  bf16*   Zd    = (bf16*)(wsb + 131072);             // 2 MB
  bf16*   Ud    = (bf16*)(wsb + 2228224);            // 2 MB
  float*  bqK   = (float*)(wsb + 4325376);           // 32 KB
  bf16*   hagg  = (bf16*)(wsb + 4358144);            // 8 MB
  float4* WkS   = (float4*)(wsb + 12746752);         // 256 KB
  float4* WvS   = (float4*)(wsb + 13008896);         // 256 KB
  float4* W1aS  = (float4*)(wsb + 13271040);         // 128 KB
  float4* WqS   = (float4*)(wsb + 13402112);         // 128 KB
  float4* W1eSa = (float4*)(wsb + 13533184);         // 32 KB
  float4* W1eSb = (float4*)(wsb + 13565952);         // 32 KB
  float4* W2Sa  = (float4*)(wsb + 13598720);         // 32 KB
  float4* W2Sb  = (float4*)(wsb + 13631488);         // 32 KB
  float*  Kg    = (float*)(wsb + 13664256);          // 8 MB
  float*  Vg    = (float*)(wsb + 22052864);          // 8 MB
  float*  hg    = (float*)(wsb + 13664256);          // 16 MB (overlay)

  k_prep <<<256, 256, 0, stream>>>(dpos, Wk, Wv, W1, W2, Wq, pos4, WkS, WvS, W1aS, WqS, W1eSa, W1eSb, W2Sa, W2Sb);
  k_dec1 <<<NC / 16, 256, 0, stream>>>(df, WkS, bk, WvS, bv, Kg, Vg);
  k_dec2 <<<NC / 16, 256, 0, stream>>>(Kg, Vg, WqS, W1aS, bq, Zd, Ud, bqK);
  k_attn <<<NF / 4, 256, 0, stream>>>(epos, pos4, ef, Zd, Ud, bqK, hagg);
  k_mlp1 <<<NF / 16, 256, 0, stream>>>(hagg, ef, W1eSa, W1eSb, b1, hg);
  k_mlp2 <<<NF / 16, 256, 0, stream>>>(hg, W2Sa, W2Sb, b2, lng, lnb, epos, lab, out);
  (void)in_sizes; (void)n_in; (void)out_size; (void)ws_size;
}

// Round 8
// 357.768 us; speedup vs baseline: 1.1178x; 1.1178x over previous
//
#include <hip/hip_runtime.h>
#include <hip/hip_bf16.h>

typedef __hip_bfloat16 bf16;
typedef unsigned short u16;

#define NC 8192
#define NF 32768
#define KNN 16
#define FMAXV 3.402823466e+38f

__device__ __forceinline__ float bfbits2f(u16 u){
  union { unsigned u; float f; } x; x.u = ((unsigned)u) << 16; return x.f;
}

// ---------- k_prep: pos4 (x,y,z,|d|^2/2) + MLP weight swizzles (grid 64 x 256 = 16384) ----------
__global__ __launch_bounds__(256) void k_prep(const float* __restrict__ dpos,
                                              const float* __restrict__ W1,
                                              const float* __restrict__ W2,
                                              float4* __restrict__ pos4,
                                              float4* __restrict__ W1eSa,
                                              float4* __restrict__ W1eSb,
                                              float4* __restrict__ W2Sa,
                                              float4* __restrict__ W2Sb){
  int g = blockIdx.x * 256 + threadIdx.x;
  if (g < 8192){
    float x = dpos[g * 3 + 0], y = dpos[g * 3 + 1], z = dpos[g * 3 + 2];
    float dd = __fadd_rn(__fadd_rn(__fmul_rn(x,x), __fmul_rn(y,y)), __fmul_rn(z,z));
    pos4[g] = make_float4(x, y, z, dd * 0.5f);
  } else if (g < 10240){
    int f = g - 8192; int c4 = f >> 6, jg = f & 63;
    W1eSa[f] = ((const float4*)(W1 + (size_t)(2 * jg) * 384 + 256))[c4];
  } else if (g < 12288){
    int f = g - 10240; int c4 = f >> 6, jg = f & 63;
    W1eSb[f] = ((const float4*)(W1 + (size_t)(2 * jg + 1) * 384 + 256))[c4];
  } else if (g < 14336){
    int f = g - 12288; int c4 = f >> 6, jg = f & 63;
    W2Sa[f] = ((const float4*)(W2 + (size_t)(2 * jg) * 128))[c4];
  } else if (g < 16384){
    int f = g - 14336; int c4 = f >> 6, jg = f & 63;
    W2Sb[f] = ((const float4*)(W2 + (size_t)(2 * jg + 1) * 128))[c4];
  }
}

// ---------- k_wprod: weight-product fold (exact associativity rewrite) ----------
// Wkq[i][c] = sum_j Wk[j][i] Wq[j][c];  bkq[c] = sum_j bk[j] Wq[j][c]
// Wvu[i][h] = sum_c2 Wv[c2][i] W1[h][c2]; bvu[h] = sum_c2 W1[h][c2] bv[c2]
// wbq[i] = sum_j bq[j] Wk[j][i];  sbq = sum_j bk[j] bq[j]
// Swizzled store: WS[(i>>2)*128 + col] component (i&3)  (matches k_dec's float4 read)
__global__ __launch_bounds__(256) void k_wprod(const float* __restrict__ Wk,
                                               const float* __restrict__ Wv,
                                               const float* __restrict__ Wq,
                                               const float* __restrict__ W1,
                                               const float* __restrict__ bk,
                                               const float* __restrict__ bv,
                                               const float* __restrict__ bq,
                                               float* __restrict__ WkqS,
                                               float* __restrict__ WvuS,
                                               float* __restrict__ bkq,
                                               float* __restrict__ bvu,
                                               float* __restrict__ wbq,
                                               float* __restrict__ sbq){
  __shared__ float red[256];
  int b = blockIdx.x, t = threadIdx.x;
  if (b < 128){
    int c = b;
    float acc = 0.f;
    for (int j = 0; j < 256; ++j)
      acc = fmaf(Wk[(size_t)j * 256 + t], Wq[(size_t)j * 128 + c], acc);   // Wk coalesced, Wq uniform
    WkqS[(size_t)((t >> 2) * 128 + c) * 4 + (t & 3)] = acc;
    red[t] = bk[t] * Wq[(size_t)t * 128 + c];
    __syncthreads();
    for (int s = 128; s > 0; s >>= 1){ if (t < s) red[t] += red[t + s]; __syncthreads(); }
    if (t == 0) bkq[c] = red[0];
  } else if (b < 256){
    int h = b - 128;
    float acc = 0.f;
    for (int c2 = 0; c2 < 256; ++c2)
      acc = fmaf(Wv[(size_t)c2 * 256 + t], W1[(size_t)h * 384 + c2], acc); // Wv coalesced, W1 uniform
    WvuS[(size_t)((t >> 2) * 128 + h) * 4 + (t & 3)] = acc;
    red[t] = bv[t] * W1[(size_t)h * 384 + t];
    __syncthreads();
    for (int s = 128; s > 0; s >>= 1){ if (t < s) red[t] += red[t + s]; __syncthreads(); }
    if (t == 0) bvu[h] = red[0];
  } else {
    float acc = 0.f;
    for (int j = 0; j < 256; ++j)
      acc = fmaf(Wk[(size_t)j * 256 + t], bq[j], acc);
    wbq[t] = acc;
    red[t] = bk[t] * bq[t];
    __syncthreads();
    for (int s = 128; s > 0; s >>= 1){ if (t < s) red[t] += red[t + s]; __syncthreads(); }
    if (t == 0) sbq[0] = red[0];
  }
}

// ---------- k_dec: Zd = df@Wkq + bkq, Ud = df@Wvu + bvu, bqK = df@wbq + sbq ----------
// waves 0-1: Zd (c = t), waves 2-3: Ud (c = t-128). df rows via uniform loads (shared by all waves).
__global__ __launch_bounds__(256) void k_dec(const float* __restrict__ df,
                                             const float4* __restrict__ WkqS,
                                             const float4* __restrict__ WvuS,
                                             const float* __restrict__ bkq,
                                             const float* __restrict__ bvu,
                                             const float* __restrict__ wbq,
                                             const float* __restrict__ sbq,
                                             bf16* __restrict__ Zd, bf16* __restrict__ Ud,
                                             float* __restrict__ bqK){
  __shared__ float part[16][16];
  int t = threadIdx.x;
  int g0 = blockIdx.x * 16;
  int half = __builtin_amdgcn_readfirstlane(t >> 7);
  int c = t & 127;
  const float4* W = half ? WvuS : WkqS;
  float acc[16];
  #pragma unroll
  for (int p = 0; p < 16; ++p) acc[p] = 0.f;
  for (int j4 = 0; j4 < 64; ++j4){
    float4 w = W[j4 * 128 + c];                                     // coalesced
    #pragma unroll
    for (int p = 0; p < 16; ++p){
      float4 a = ((const float4*)(df + (size_t)(g0 + p) * 256))[j4]; // uniform
      acc[p] += w.x*a.x + w.y*a.y + w.z*a.z + w.w*a.w;
    }
  }
  float bias = half ? bvu[c] : bkq[c];
  bf16* dst = half ? Ud : Zd;
  #pragma unroll
  for (int p = 0; p < 16; ++p)
    dst[(size_t)(g0 + p) * 128 + c] = __float2bfloat16(acc[p] + bias);
  // bqK: distributed 16-seg partial dot per row
  {
    int r = t >> 4, seg = t & 15;
    float s = 0.f;
    const float* dr = df + (size_t)(g0 + r) * 256 + seg * 16;
    const float* wq = wbq + seg * 16;
    #pragma unroll
    for (int e = 0; e < 16; ++e) s = fmaf(dr[e], wq[e], s);
    part[r][seg] = s;
  }
  __syncthreads();
  if (t < 16){
    float s = sbq[0];
    #pragma unroll
    for (int seg = 0; seg < 16; ++seg) s += part[t][seg];
    bqK[g0 + t] = s;
  }
}

// ---------- fused KNN + attention: 8 points/block, candidates split across 4 waves ----------
// tau0[p] = 17th smallest of the union of each wave's 16 smallest lane-minima (provable bound).
// Pass B appends candidates <= tau0 via LDS atomics; exact (val,idx) bitonic top-16.
__global__ __launch_bounds__(256) void k_attn(const float* __restrict__ epos,
                                              const float4* __restrict__ pos4,
                                              const float* __restrict__ ef,
                                              const bf16* __restrict__ Zd,
                                              const bf16* __restrict__ Ud,
                                              const float* __restrict__ bqK,
                                              bf16* __restrict__ hagg){
  __shared__ float smin[8 * 64];
  __shared__ float tauLDS[8];
  __shared__ int   cnt[8];
  __shared__ float lval[8][64];
  __shared__ int   lidx[8][64];

  int t = threadIdx.x, lane = t & 63, w = t >> 6;
  int n0 = blockIdx.x * 8;
  float nex[8], ney[8], nez[8];
  #pragma unroll
  for (int p = 0; p < 8; ++p){
    nex[p] = -epos[(n0 + p) * 3 + 0];
    ney[p] = -epos[(n0 + p) * 3 + 1];
    nez[p] = -epos[(n0 + p) * 3 + 2];
  }
  const float4* base = pos4 + w * 2048;

  // PASS A: per-lane minima of val = dd/2 - e.d (3 fused FMAs), 8 points per candidate read
  float vmin[8] = {FMAXV,FMAXV,FMAXV,FMAXV,FMAXV,FMAXV,FMAXV,FMAXV};
  #pragma unroll 2
  for (int s = 0; s < 32; ++s){
    float4 P = base[s * 64 + lane];
    #pragma unroll
    for (int p = 0; p < 8; ++p){
      float val = fmaf(nez[p], P.z, fmaf(ney[p], P.y, fmaf(nex[p], P.x, P.w)));
      vmin[p] = fminf(vmin[p], val);
    }
  }
  // bitonic sort of 64 lane-minima, 8 point-registers at once
  #pragma unroll
  for (int k = 2; k <= 64; k <<= 1){
    #pragma unroll
    for (int j = k >> 1; j > 0; j >>= 1){
      bool keepmin = ((lane & j) == 0) == ((lane & k) == 0);
      #pragma unroll
      for (int p = 0; p < 8; ++p){
        float pv = __shfl_xor(vmin[p], j);
        vmin[p] = keepmin ? fminf(vmin[p], pv) : fmaxf(vmin[p], pv);
      }
    }
  }
  if (lane < 16){
    #pragma unroll
    for (int p = 0; p < 8; ++p) smin[p * 64 + w * 16 + lane] = vmin[p];
  }
  if (t < 8) cnt[t] = 0;
  __syncthreads();
  // wave w sorts unions for points 2w, 2w+1; tau0 = 17th smallest
  #pragma unroll
  for (int u = 0; u < 2; ++u){
    int p = w * 2 + u;
    float v = smin[p * 64 + lane];
    #pragma unroll
    for (int k = 2; k <= 64; k <<= 1){
      #pragma unroll
      for (int j = k >> 1; j > 0; j >>= 1){
        float pv = __shfl_xor(v, j);
        bool keepmin = ((lane & j) == 0) == ((lane & k) == 0);
        v = keepmin ? fminf(v, pv) : fmaxf(v, pv);
      }
    }
    if (lane == 16) tauLDS[p] = v;
  }
  __syncthreads();
  float tau0[8];
  #pragma unroll
  for (int p = 0; p < 8; ++p) tau0[p] = tauLDS[p];

  // PASS B: filtered append (identical val expression)
  #pragma unroll 2
  for (int s = 0; s < 32; ++s){
    float4 P = base[s * 64 + lane];
    int cand = w * 2048 + s * 64 + lane;
    #pragma unroll
    for (int p = 0; p < 8; ++p){
      float val = fmaf(nez[p], P.z, fmaf(ney[p], P.y, fmaf(nex[p], P.x, P.w)));
      if (val <= tau0[p]){
        int slot = atomicAdd(&cnt[p], 1);
        if (slot < 64){ lval[p][slot] = val; lidx[p][slot] = cand; }
      }
    }
  }
  __syncthreads();

  // wave w finalizes points 2w, 2w+1: exact (val,idx) sort, scores, softmax, hidden agg
  for (int u = 0; u < 2; ++u){
    int p = w * 2 + u;
    int n = n0 + p;
    int c = cnt[p]; if (c > 64) c = 64;
    float v  = (lane < c) ? lval[p][lane] : FMAXV;
    int   id = (lane < c) ? lidx[p][lane] : 0x7fffffff;
    #pragma unroll
    for (int k = 2; k <= 64; k <<= 1){
      #pragma unroll
      for (int j = k >> 1; j > 0; j >>= 1){
        float pv  = __shfl_xor(v, j);
        int   pid = __shfl_xor(id, j);
        bool keepmin = ((lane & j) == 0) == ((lane & k) == 0);
        bool pless = (pv < v) || (pv == v && pid < id);
        bool take = keepmin ? pless : !pless;
        if (take){ v = pv; id = pid; }
      }
    }
    int topi = id;

    float2 eu = *(const float2*)(ef + (size_t)n * 128 + lane * 2);
    float sc = -FMAXV;
    #pragma unroll
    for (int k = 0; k < KNN; ++k){
      int ik = __shfl(topi, k);
      ushort2 zu = *(const ushort2*)((const u16*)Zd + (size_t)ik * 128 + lane * 2);
      float pr = eu.x * bfbits2f(zu.x) + eu.y * bfbits2f(zu.y);
      #pragma unroll
      for (int off = 32; off >= 1; off >>= 1) pr += __shfl_xor(pr, off);
      float bz = bqK[ik];
      if (lane == k) sc = (pr + bz) * (1.0f / 16.0f);
    }
    float mx = sc;
    #pragma unroll
    for (int off = 8; off >= 1; off >>= 1) mx = fmaxf(mx, __shfl_xor(mx, off));
    float e = (lane < KNN) ? __expf(sc - mx) : 0.f;
    float l = e;
    #pragma unroll
    for (int off = 8; off >= 1; off >>= 1) l += __shfl_xor(l, off);
    float wgt = (lane < KNN) ? (e / l) : 0.f;

    float a0 = 0.f, a1 = 0.f;
    #pragma unroll
    for (int k = 0; k < KNN; ++k){
      int ik = __shfl(topi, k);
      float wk = __shfl(wgt, k);
      ushort2 uu = *(const ushort2*)((const u16*)Ud + (size_t)ik * 128 + lane * 2);
      a0 = fmaf(wk, bfbits2f(uu.x), a0);
      a1 = fmaf(wk, bfbits2f(uu.y), a1);
    }
    bf16* hr = hagg + (size_t)n * 128 + lane * 2;
    hr[0] = __float2bfloat16(a0);
    hr[1] = __float2bfloat16(a1);
  }
}

// ---------- fused MLP: h = relu(hagg + W1e@ef + b1) -> LDS; up = W2@h + b2; LN; out + tail ----------
__global__ __launch_bounds__(256) void k_mlp(const bf16* __restrict__ hagg,
                                             const float* __restrict__ ef,
                                             const float4* __restrict__ W1eSa,
                                             const float4* __restrict__ W1eSb,
                                             const float* __restrict__ b1,
                                             const float4* __restrict__ W2Sa,
                                             const float4* __restrict__ W2Sb,
                                             const float* __restrict__ b2,
                                             const float* __restrict__ lng, const float* __restrict__ lnb,
                                             const float* __restrict__ epos, const int* __restrict__ lab,
                                             float* __restrict__ out){
  __shared__ float hbuf[16 * 128];
  __shared__ float ubuf[16 * 128];
  __shared__ float stats[32];
  int t = threadIdx.x;
  int n0 = blockIdx.x * 16;
  {
    int gid = blockIdx.x * 256 + t;
    if (gid < NF){
      float* op = out + (size_t)NF * 128;
      op[gid * 3 + 0] = epos[gid * 3 + 0];
      op[gid * 3 + 1] = epos[gid * 3 + 1];
      op[gid * 3 + 2] = epos[gid * 3 + 2];
      out[(size_t)NF * 128 + (size_t)NF * 3 + gid] = (float)lab[gid];
    }
  }
  int jg = t & 63;
  int pg4 = __builtin_amdgcn_readfirstlane((t >> 6) * 4);
  int j0 = jg * 2;
  float acc[2][4];
  #pragma unroll
  for (int a = 0; a < 2; ++a)
    #pragma unroll
    for (int p = 0; p < 4; ++p) acc[a][p] = 0.f;
  for (int c4 = 0; c4 < 32; ++c4){
    float4 wa = W1eSa[c4 * 64 + jg];
    float4 wb = W1eSb[c4 * 64 + jg];
    #pragma unroll
    for (int p = 0; p < 4; ++p){
      float4 x = ((const float4*)(ef + (size_t)(n0 + pg4 + p) * 128))[c4];  // uniform
      acc[0][p] += wa.x*x.x + wa.y*x.y + wa.z*x.z + wa.w*x.w;
      acc[1][p] += wb.x*x.x + wb.y*x.y + wb.z*x.z + wb.w*x.w;
    }
  }
  float b1a = b1[j0], b1b = b1[j0 + 1];
  #pragma unroll
  for (int p = 0; p < 4; ++p){
    size_t row = (size_t)(n0 + pg4 + p);
    ushort2 hgv = *(const ushort2*)((const u16*)hagg + row * 128 + j0);
    hbuf[(pg4 + p) * 128 + j0]     = fmaxf(acc[0][p] + b1a + bfbits2f(hgv.x), 0.f);
    hbuf[(pg4 + p) * 128 + j0 + 1] = fmaxf(acc[1][p] + b1b + bfbits2f(hgv.y), 0.f);
  }
  __syncthreads();
  float acc2[2][4];
  #pragma unroll
  for (int a = 0; a < 2; ++a)
    #pragma unroll
    for (int p = 0; p < 4; ++p) acc2[a][p] = 0.f;
  const float4* hb4 = (const float4*)hbuf;
  for (int c4 = 0; c4 < 32; ++c4){
    float4 wa = W2Sa[c4 * 64 + jg];
    float4 wb = W2Sb[c4 * 64 + jg];
    #pragma unroll
    for (int p = 0; p < 4; ++p){
      float4 x = hb4[(pg4 + p) * 32 + c4];   // wave-uniform LDS broadcast
      acc2[0][p] += wa.x*x.x + wa.y*x.y + wa.z*x.z + wa.w*x.w;
      acc2[1][p] += wb.x*x.x + wb.y*x.y + wb.z*x.z + wb.w*x.w;
    }
  }
  float b2a = b2[j0], b2b = b2[j0 + 1];
  float u[2][4];
  #pragma unroll
  for (int p = 0; p < 4; ++p){
    u[0][p] = acc2[0][p] + b2a;
    u[1][p] = acc2[1][p] + b2b;
    ubuf[(pg4 + p) * 128 + j0]     = u[0][p];
    ubuf[(pg4 + p) * 128 + j0 + 1] = u[1][p];
  }
  __syncthreads();
  {
    int p = t >> 4, qi = t & 15;
    const float* ub = &ubuf[p * 128 + qi * 8];
    float s = 0.f, s2 = 0.f;
    #pragma unroll
    for (int e2i = 0; e2i < 8; ++e2i){ float v = ub[e2i]; s += v; s2 += v * v; }
    #pragma unroll
    for (int off = 1; off < 16; off <<= 1){ s += __shfl_xor(s, off); s2 += __shfl_xor(s2, off); }
    if (qi == 0){
      float mu = s * (1.f / 128.f);
      float var = s2 * (1.f / 128.f) - mu * mu;
      stats[p] = mu;
      stats[16 + p] = rsqrtf(fmaxf(var, 0.f) + 1e-5f);
    }
  }
  __syncthreads();
  float ga = lng[j0], gb = lng[j0 + 1];
  float ba = lnb[j0], bbv = lnb[j0 + 1];
  #pragma unroll
  for (int p = 0; p < 4; ++p){
    float mu = stats[pg4 + p], rs = stats[16 + pg4 + p];
    out[(size_t)(n0 + pg4 + p) * 128 + j0]     = (u[0][p] - mu) * rs * ga + ba;
    out[(size_t)(n0 + pg4 + p) * 128 + j0 + 1] = (u[1][p] - mu) * rs * gb + bbv;
  }
}

extern "C" void kernel_launch(void* const* d_in, const int* in_sizes, int n_in,
                              void* d_out, int out_size, void* d_ws, size_t ws_size,
                              hipStream_t stream){
  const float* df   = (const float*)d_in[0];
  const float* dpos = (const float*)d_in[1];
  const float* ef   = (const float*)d_in[2];
  const float* epos = (const float*)d_in[3];
  const int*   lab  = (const int*)d_in[4];
  const float* Wq = (const float*)d_in[5];
  const float* bq = (const float*)d_in[6];
  const float* Wk = (const float*)d_in[7];
  const float* bk = (const float*)d_in[8];
  const float* Wv = (const float*)d_in[9];
  const float* bv = (const float*)d_in[10];
  const float* W1 = (const float*)d_in[11];
  const float* b1 = (const float*)d_in[12];
  const float* W2 = (const float*)d_in[13];
  const float* b2 = (const float*)d_in[14];
  const float* lng = (const float*)d_in[15];
  const float* lnb = (const float*)d_in[16];
  float* out = (float*)d_out;

  // workspace layout (~12.6 MB)
  char* wsb = (char*)d_ws;
  float4* pos4  = (float4*)(wsb);                    // 128 KB
  bf16*   Zd    = (bf16*)(wsb + 131072);             // 2 MB
  bf16*   Ud    = (bf16*)(wsb + 2228224);            // 2 MB
  float*  bqK   = (float*)(wsb + 4325376);           // 32 KB
  bf16*   hagg  = (bf16*)(wsb + 4358144);            // 8 MB
  float4* W1eSa = (float4*)(wsb + 12746752);         // 32 KB
  float4* W1eSb = (float4*)(wsb + 12779520);         // 32 KB
  float4* W2Sa  = (float4*)(wsb + 12812288);         // 32 KB
  float4* W2Sb  = (float4*)(wsb + 12845056);         // 32 KB
  float*  WkqS  = (float*)(wsb + 12877824);          // 128 KB
  float*  WvuS  = (float*)(wsb + 13008896);          // 128 KB
  float*  bkq   = (float*)(wsb + 13139968);          // 512 B
  float*  bvu   = (float*)(wsb + 13140480);          // 512 B
  float*  wbq   = (float*)(wsb + 13140992);          // 1 KB
  float*  sbq   = (float*)(wsb + 13142016);          // 4 B

  k_prep  <<<64,  256, 0, stream>>>(dpos, W1, W2, pos4, W1eSa, W1eSb, W2Sa, W2Sb);
  k_wprod <<<257, 256, 0, stream>>>(Wk, Wv, Wq, W1, bk, bv, bq, WkqS, WvuS, bkq, bvu, wbq, sbq);
  k_dec   <<<NC / 16, 256, 0, stream>>>(df, (const float4*)WkqS, (const float4*)WvuS, bkq, bvu, wbq, sbq, Zd, Ud, bqK);
  k_attn  <<<NF / 8, 256, 0, stream>>>(epos, pos4, ef, Zd, Ud, bqK, hagg);
  k_mlp   <<<NF / 16, 256, 0, stream>>>(hagg, ef, W1eSa, W1eSb, b1, W2Sa, W2Sb, b2, lng, lnb, epos, lab, out);
  (void)in_sizes; (void)n_in; (void)out_size; (void)ws_size;
}